// Round 4
// baseline (262.697 us; speedup 1.0000x reference)
//
#include <hip/hip_runtime.h>
#include <hip/hip_bf16.h>

typedef __bf16 bf16;
typedef __bf16 bf16x8 __attribute__((ext_vector_type(8)));
typedef float f32x4 __attribute__((ext_vector_type(4)));

#define C_DIM 128
#define LDA 136   // xn1/sY/O row stride (bf16 elems)
#define LDQ 36    // q/k row stride  (18-word stride -> 16 distinct banks)
#define LDVT 68   // vT row stride   (34-word stride -> 16 distinct banks)
#define LDP 68    // P row stride
#define LDH 264   // h-half row stride

__device__ __forceinline__ f32x4 mfma16(bf16x8 a, bf16x8 b, f32x4 c) {
  return __builtin_amdgcn_mfma_f32_16x16x32_bf16(a, b, c, 0, 0, 0);
}

// LDS: two time-multiplexed regions, 54272 B total -> 3 blocks/CU:
//   RA @ 0     (17408): xn1 -> sVT[4][32][68] -> sY[64][136]
//   RB @ 17408 (36864): sQ[4][64][36]+sK[4][64][36] -> sP[4][64][68]
//                       -> O[64][136] -> xn2[64][136] -> sH[64][264]
// Region reuse is fenced by a barrier after the previous tenant's frag loads.

__global__ __launch_bounds__(256, 3) void swin_fused(
    const float* __restrict__ x,
    const bf16*  __restrict__ Wqkv_t, const float* __restrict__ b_qkv,
    const bf16*  __restrict__ Wout_t, const float* __restrict__ b_out,
    const float* __restrict__ btabx,
    const float* __restrict__ g1, const float* __restrict__ be1,
    const float* __restrict__ g2, const float* __restrict__ be2,
    const bf16*  __restrict__ Wfc1_t, const float* __restrict__ b_fc1,
    const bf16*  __restrict__ Wfc2_t, const float* __restrict__ b_fc2,
    float* __restrict__ out)
{
  __shared__ __attribute__((aligned(16))) char smem[54272];
  // RA tenants
  bf16 (*sA)[LDA]       = (bf16(*)[LDA])(smem);              // xn1
  bf16 (*sVT)[32][LDVT] = (bf16(*)[32][LDVT])(smem);         // v^T
  bf16 (*sY)[LDA]       = (bf16(*)[LDA])(smem);              // y
  // RB tenants
  bf16 (*sQ)[64][LDQ]   = (bf16(*)[64][LDQ])(smem + 17408);
  bf16 (*sK)[64][LDQ]   = (bf16(*)[64][LDQ])(smem + 17408 + 18432);
  bf16 (*sP)[64][LDP]   = (bf16(*)[64][LDP])(smem + 17408);
  bf16 (*sO)[LDA]       = (bf16(*)[LDA])(smem + 17408);      // attn out
  bf16 (*sX2)[LDA]      = (bf16(*)[LDA])(smem + 17408);      // xn2
  bf16 (*sH)[LDH]       = (bf16(*)[LDH])(smem + 17408);      // mlp hidden half

  const int tid = threadIdx.x;
  const int w   = tid >> 6;   // wave 0..3
  const int l   = tid & 63;
  const int l15 = l & 15;
  const int lhi = l >> 4;     // 0..3

  const int win = blockIdx.x;
  const int b   = win >> 6;
  const int wy  = (win >> 3) & 7;
  const int wx  = win & 7;
  const int rowbase = b * 4096 + wy * 512 + wx * 8; // t = rowbase + (n>>3)*64 + (n&7)

  float yreg[2][4][4];  // post-attention residual, f32, phase4 -> epilogue

  // ---------------- Phase 1: LN1 -> RA (xn1) ----------------
  {
    const int tok = tid >> 2, seg = tid & 3;
    const int t = rowbase + (tok >> 3) * 64 + (tok & 7);
    const float* xr = x + (size_t)t * C_DIM + seg * 32;
    float f[32]; float s = 0.f, s2 = 0.f;
    #pragma unroll
    for (int i = 0; i < 8; i++) {
      f32x4 v = *(const f32x4*)(xr + i * 4);
      #pragma unroll
      for (int j = 0; j < 4; j++) { float a = v[j]; f[i*4+j] = a; s += a; s2 += a*a; }
    }
    s  += __shfl_xor(s, 1);  s  += __shfl_xor(s, 2);
    s2 += __shfl_xor(s2, 1); s2 += __shfl_xor(s2, 2);
    float mu = s * (1.f/128.f);
    float rs = rsqrtf(s2 * (1.f/128.f) - mu*mu + 1e-5f);
    #pragma unroll
    for (int i = 0; i < 4; i++) {
      f32x4 gv0 = *(const f32x4*)(g1  + seg*32 + i*8);
      f32x4 gv1 = *(const f32x4*)(g1  + seg*32 + i*8 + 4);
      f32x4 bv0 = *(const f32x4*)(be1 + seg*32 + i*8);
      f32x4 bv1 = *(const f32x4*)(be1 + seg*32 + i*8 + 4);
      bf16x8 o;
      #pragma unroll
      for (int j = 0; j < 4; j++) {
        o[j]   = (bf16)((f[i*8+j]   - mu) * rs * gv0[j] + bv0[j]);
        o[j+4] = (bf16)((f[i*8+j+4] - mu) * rs * gv1[j] + bv1[j]);
      }
      *(bf16x8*)&sA[tok][seg*32 + i*8] = o;
    }
  }
  __syncthreads();  // BAR1: xn1 ready

  // ---------------- Phase 2: QKV GEMM (M=64,N=384,K=128), wave w owns nt 6w..6w+5 ----------------
  {
    bf16x8 a[4][4];
    #pragma unroll
    for (int mt = 0; mt < 4; mt++)
      #pragma unroll
      for (int ks = 0; ks < 4; ks++)
        a[mt][ks] = *(const bf16x8*)&sA[mt*16 + l15][ks*32 + lhi*8];
    __syncthreads();  // BAR2: xn1 consumed -> RA free for sVT
    const float scale = 0.17677669529663687f; // 1/sqrt(32)
    #pragma unroll
    for (int nti = 0; nti < 6; nti++) {
      const int nt = w * 6 + nti;
      const int colg = nt * 16 + l15;           // 0..383
      const bf16* wp = Wqkv_t + (size_t)colg * 128 + lhi * 8;
      bf16x8 bw[4];
      #pragma unroll
      for (int ks = 0; ks < 4; ks++) bw[ks] = *(const bf16x8*)(wp + ks * 32);
      const float bias = b_qkv[colg];
      const int kind = colg >> 7;               // 0=q 1=k 2=v (uniform per nt)
      const int h    = (colg >> 5) & 3;
      const int d    = colg & 31;
      #pragma unroll
      for (int mt = 0; mt < 4; mt++) {
        f32x4 acc = {0.f, 0.f, 0.f, 0.f};
        #pragma unroll
        for (int ks = 0; ks < 4; ks++) acc = mfma16(a[mt][ks], bw[ks], acc);
        #pragma unroll
        for (int r = 0; r < 4; r++) {
          const int token = mt*16 + lhi*4 + r;
          float v = acc[r] + bias;
          if (kind == 0)      sQ[h][token][d] = (bf16)(v * scale);
          else if (kind == 1) sK[h][token][d] = (bf16)v;
          else                sVT[h][d][token] = (bf16)v;
        }
      }
    }
  }
  __syncthreads();  // BAR3: q/k/vT ready

  // ---------------- Phase 3: attention, wave w = head ----------------
  {
    const int h = w;
    bf16x8 aq[4], bk[4];
    #pragma unroll
    for (int mt = 0; mt < 4; mt++) aq[mt] = *(const bf16x8*)&sQ[h][mt*16 + l15][lhi*8];
    #pragma unroll
    for (int ct = 0; ct < 4; ct++) bk[ct] = *(const bf16x8*)&sK[h][ct*16 + l15][lhi*8];
    f32x4 sc[4][4];
    #pragma unroll
    for (int mt = 0; mt < 4; mt++)
      #pragma unroll
      for (int ct = 0; ct < 4; ct++) {
        f32x4 z = {0.f, 0.f, 0.f, 0.f};
        sc[mt][ct] = mfma16(aq[mt], bk[ct], z);
      }
    __syncthreads();  // BAR4: sQ/sK consumed -> RB free for sP
    // bias + softmax rows -> P (bf16, row-major for PV A-operand)
    #pragma unroll
    for (int mt = 0; mt < 4; mt++) {
      #pragma unroll
      for (int r = 0; r < 4; r++) {
        const int n = mt*16 + lhi*4 + r;
        f32x4 bv = *(const f32x4*)(btabx + (((h*64 + n)*16 + l15) << 2));
        float rv[4];
        #pragma unroll
        for (int ct = 0; ct < 4; ct++) rv[ct] = sc[mt][ct][r] + bv[ct];
        float mx = fmaxf(fmaxf(rv[0], rv[1]), fmaxf(rv[2], rv[3]));
        #pragma unroll
        for (int o = 1; o < 16; o <<= 1) mx = fmaxf(mx, __shfl_xor(mx, o));
        float sum = 0.f;
        #pragma unroll
        for (int ct = 0; ct < 4; ct++) { rv[ct] = __expf(rv[ct] - mx); sum += rv[ct]; }
        #pragma unroll
        for (int o = 1; o < 16; o <<= 1) sum += __shfl_xor(sum, o);
        const float inv = 1.f / sum;
        #pragma unroll
        for (int ct = 0; ct < 4; ct++) sP[h][n][ct*16 + l15] = (bf16)(rv[ct] * inv);
      }
    }
    // preload ALL PV frags (own-wave data; lgkmcnt covers the RAW on sP)
    bf16x8 ap[2][4], bvv[2][2];
    #pragma unroll
    for (int ks = 0; ks < 2; ks++) {
      #pragma unroll
      for (int mt = 0; mt < 4; mt++) ap[ks][mt] = *(const bf16x8*)&sP[h][mt*16 + l15][ks*32 + lhi*8];
      #pragma unroll
      for (int c2 = 0; c2 < 2; c2++) bvv[ks][c2] = *(const bf16x8*)&sVT[h][c2*16 + l15][ks*32 + lhi*8];
    }
    __syncthreads();  // BAR5: sP/sVT consumed -> RB front free for O
    f32x4 o_[4][2];
    #pragma unroll
    for (int mt = 0; mt < 4; mt++) { f32x4 z = {0.f,0.f,0.f,0.f}; o_[mt][0] = z; o_[mt][1] = z; }
    #pragma unroll
    for (int ks = 0; ks < 2; ks++)
      #pragma unroll
      for (int mt = 0; mt < 4; mt++)
        #pragma unroll
        for (int c2 = 0; c2 < 2; c2++) o_[mt][c2] = mfma16(ap[ks][mt], bvv[ks][c2], o_[mt][c2]);
    #pragma unroll
    for (int mt = 0; mt < 4; mt++)
      #pragma unroll
      for (int c2 = 0; c2 < 2; c2++)
        #pragma unroll
        for (int r = 0; r < 4; r++)
          sO[mt*16 + lhi*4 + r][h*32 + c2*16 + l15] = (bf16)o_[mt][c2][r];
  }
  __syncthreads();  // BAR6: O ready

  // ---------------- Phase 4: out-proj + shortcut -> sY (RA) + yreg (f32) ----------------
  {
    bf16x8 a[4][4];
    #pragma unroll
    for (int mt = 0; mt < 4; mt++)
      #pragma unroll
      for (int ks = 0; ks < 4; ks++)
        a[mt][ks] = *(const bf16x8*)&sO[mt*16 + l15][ks*32 + lhi*8];
    #pragma unroll
    for (int nto = 0; nto < 2; nto++) {
      const int col = (w*2 + nto) * 16 + l15;
      const bf16* wp = Wout_t + (size_t)col * 128 + lhi * 8;
      bf16x8 bw[4];
      #pragma unroll
      for (int ks = 0; ks < 4; ks++) bw[ks] = *(const bf16x8*)(wp + ks * 32);
      const float bo = b_out[col];
      #pragma unroll
      for (int mt = 0; mt < 4; mt++) {
        f32x4 acc = {0.f, 0.f, 0.f, 0.f};
        #pragma unroll
        for (int ks = 0; ks < 4; ks++) acc = mfma16(a[mt][ks], bw[ks], acc);
        #pragma unroll
        for (int r = 0; r < 4; r++) {
          const int token = mt*16 + lhi*4 + r;
          const int t = rowbase + (token >> 3) * 64 + (token & 7);
          float v = acc[r] + bo + x[(size_t)t * C_DIM + col];
          yreg[nto][mt][r] = v;
          sY[token][col] = (bf16)v;   // RA (sVT dead since BAR5)
        }
      }
    }
  }
  __syncthreads();  // BAR8: sY ready; O consumed -> RB free for xn2

  // ---------------- Phase 5: LN2 (sY -> sX2) ----------------
  {
    const int tok = tid >> 2, seg = tid & 3;
    float f[32]; float s = 0.f, s2 = 0.f;
    #pragma unroll
    for (int i = 0; i < 4; i++) {
      bf16x8 v = *(const bf16x8*)&sY[tok][seg*32 + i*8];
      #pragma unroll
      for (int j = 0; j < 8; j++) { float a = (float)v[j]; f[i*8+j] = a; s += a; s2 += a*a; }
    }
    s  += __shfl_xor(s, 1);  s  += __shfl_xor(s, 2);
    s2 += __shfl_xor(s2, 1); s2 += __shfl_xor(s2, 2);
    float mu = s * (1.f/128.f);
    float rs = rsqrtf(s2 * (1.f/128.f) - mu*mu + 1e-5f);
    #pragma unroll
    for (int i = 0; i < 4; i++) {
      f32x4 gv0 = *(const f32x4*)(g2  + seg*32 + i*8);
      f32x4 gv1 = *(const f32x4*)(g2  + seg*32 + i*8 + 4);
      f32x4 bv0 = *(const f32x4*)(be2 + seg*32 + i*8);
      f32x4 bv1 = *(const f32x4*)(be2 + seg*32 + i*8 + 4);
      bf16x8 o;
      #pragma unroll
      for (int j = 0; j < 4; j++) {
        o[j]   = (bf16)((f[i*8+j]   - mu) * rs * gv0[j] + bv0[j]);
        o[j+4] = (bf16)((f[i*8+j+4] - mu) * rs * gv1[j] + bv1[j]);
      }
      *(bf16x8*)&sX2[tok][seg*32 + i*8] = o;
    }
  }
  __syncthreads();  // BAR9: xn2 ready

  // ---------------- Phase 6: MLP (FC1+GELU -> sH halves, FC2 accumulated) ----------------
  {
    bf16x8 a[4][4];
    #pragma unroll
    for (int mt = 0; mt < 4; mt++)
      #pragma unroll
      for (int ks = 0; ks < 4; ks++)
        a[mt][ks] = *(const bf16x8*)&sX2[mt*16 + l15][ks*32 + lhi*8];
    __syncthreads();  // BAR10: xn2 consumed -> RB free for sH
    f32x4 accF[2][4];
    #pragma unroll
    for (int i = 0; i < 2; i++)
      #pragma unroll
      for (int mt = 0; mt < 4; mt++) { f32x4 z = {0.f,0.f,0.f,0.f}; accF[i][mt] = z; }

    #pragma unroll
    for (int hf = 0; hf < 2; hf++) {
      // FC1 quarter: wave w owns local hidden cols [w*64, w*64+64) of this half
      #pragma unroll
      for (int nti = 0; nti < 4; nti++) {
        const int ntg    = hf*16 + w*4 + nti;          // global hidden tile 0..31
        const int colh   = ntg*16 + l15;               // global hidden col
        const int colloc = (w*4 + nti)*16 + l15;       // col within sH half
        const bf16* wp = Wfc1_t + (size_t)colh * 128 + lhi * 8;
        bf16x8 bw[4];
        #pragma unroll
        for (int ks = 0; ks < 4; ks++) bw[ks] = *(const bf16x8*)(wp + ks * 32);
        const float bb = b_fc1[colh];
        #pragma unroll
        for (int mt = 0; mt < 4; mt++) {
          f32x4 acc = {0.f, 0.f, 0.f, 0.f};
          #pragma unroll
          for (int ks = 0; ks < 4; ks++) acc = mfma16(a[mt][ks], bw[ks], acc);
          #pragma unroll
          for (int r = 0; r < 4; r++) {
            float v = acc[r] + bb;
            // GELU (erf) via tanh form, hardware exp; |err| < ~1e-3 absolute
            float u = v * (0.7978845608028654f + 0.0356774081363001f * v * v);
            float e = __expf(2.f * u);
            float th = 1.f - 2.f / (e + 1.f);
            float g = 0.5f * v * (1.f + th);
            sH[mt*16 + lhi*4 + r][colloc] = (bf16)g;
          }
        }
      }
      __syncthreads();
      // FC2 partial over this half's 256 hidden dims; wave w owns out cols [w*32, w*32+32)
      #pragma unroll
      for (int ks = 0; ks < 8; ks++) {
        bf16x8 ah[4], bw2[2];
        #pragma unroll
        for (int mt = 0; mt < 4; mt++) ah[mt] = *(const bf16x8*)&sH[mt*16 + l15][ks*32 + lhi*8];
        #pragma unroll
        for (int nto = 0; nto < 2; nto++)
          bw2[nto] = *(const bf16x8*)(Wfc2_t + (size_t)((w*2 + nto)*16 + l15) * 512 + hf*256 + ks*32 + lhi*8);
        #pragma unroll
        for (int nto = 0; nto < 2; nto++)
          #pragma unroll
          for (int mt = 0; mt < 4; mt++) accF[nto][mt] = mfma16(ah[mt], bw2[nto], accF[nto][mt]);
      }
      __syncthreads();
    }
    // epilogue: + b_fc2 + y -> out (f32)
    #pragma unroll
    for (int nto = 0; nto < 2; nto++) {
      const int col = (w*2 + nto)*16 + l15;
      const float bb = b_fc2[col];
      #pragma unroll
      for (int mt = 0; mt < 4; mt++)
        #pragma unroll
        for (int r = 0; r < 4; r++) {
          const int token = mt*16 + lhi*4 + r;
          const int t = rowbase + (token >> 3) * 64 + (token & 7);
          out[(size_t)t * C_DIM + col] = accF[nto][mt][r] + bb + yreg[nto][mt][r];
        }
    }
  }
}

// Transpose f32 weights -> bf16 (W_t[n][k] = W[k][n]) and expand the rel-pos
// bias table to btabx[h][n][l15][ct] = btab[idx(n, ct*16+l15)*4 + h]  (f32)
__global__ void prep_transpose(
    const float* __restrict__ Wqkv, const float* __restrict__ Wout,
    const float* __restrict__ Wfc1, const float* __restrict__ Wfc2,
    const float* __restrict__ btab,
    bf16* __restrict__ Wqkv_t, bf16* __restrict__ Wout_t,
    bf16* __restrict__ Wfc1_t, bf16* __restrict__ Wfc2_t,
    float* __restrict__ btabx)
{
  int i = blockIdx.x * 256 + threadIdx.x;
  if (i < 49152) { int n = i >> 7, k = i & 127; Wqkv_t[i] = (bf16)Wqkv[k*384 + n]; return; }
  i -= 49152;
  if (i < 16384) { int n = i >> 7, k = i & 127; Wout_t[i] = (bf16)Wout[k*128 + n]; return; }
  i -= 16384;
  if (i < 65536) { int n = i >> 7, k = i & 127; Wfc1_t[i] = (bf16)Wfc1[k*512 + n]; return; }
  i -= 65536;
  if (i < 65536) { int n = i >> 9, k = i & 511; Wfc2_t[i] = (bf16)Wfc2[k*128 + n]; return; }
  i -= 65536;
  if (i < 16384) {
    int ct  = i & 3;
    int l15 = (i >> 2) & 15;
    int n   = (i >> 6) & 63;
    int h   = i >> 12;
    int m = ct * 16 + l15;
    int nr = n >> 3, nc = n & 7, mr = m >> 3, mc = m & 7;
    int idx = (nr - mr + 7) * 15 + (nc - mc + 7);
    btabx[i] = btab[idx * 4 + h];
  }
}

extern "C" void kernel_launch(void* const* d_in, const int* in_sizes, int n_in,
                              void* d_out, int out_size, void* d_ws, size_t ws_size,
                              hipStream_t stream)
{
  const float* x    = (const float*)d_in[0];
  const float* Wqkv = (const float*)d_in[1];
  const float* bqkv = (const float*)d_in[2];
  const float* Wout = (const float*)d_in[3];
  const float* bout = (const float*)d_in[4];
  const float* btab = (const float*)d_in[5];
  const float* g1   = (const float*)d_in[6];
  const float* be1  = (const float*)d_in[7];
  const float* g2   = (const float*)d_in[8];
  const float* be2  = (const float*)d_in[9];
  const float* Wfc1 = (const float*)d_in[10];
  const float* bfc1 = (const float*)d_in[11];
  const float* Wfc2 = (const float*)d_in[12];
  const float* bfc2 = (const float*)d_in[13];
  // d_in[14]=H, d_in[15]=W (fixed 64)

  bf16* ws = (bf16*)d_ws;
  bf16* Wqkv_t = ws;            // 384x128
  bf16* Wout_t = ws + 49152;    // 128x128
  bf16* Wfc1_t = ws + 65536;    // 512x128
  bf16* Wfc2_t = ws + 131072;   // 128x512
  float* btabx = (float*)(ws + 196608);  // 4*64*16*4 f32 = 64KB

  prep_transpose<<<832, 256, 0, stream>>>(Wqkv, Wout, Wfc1, Wfc2, btab,
                                          Wqkv_t, Wout_t, Wfc1_t, Wfc2_t, btabx);

  const int B = in_sizes[0] / (4096 * 128);
  swin_fused<<<dim3(B * 64), 256, 0, stream>>>(
      x, Wqkv_t, bqkv, Wout_t, bout, btabx, g1, be1, g2, be2,
      Wfc1_t, bfc1, Wfc2_t, bfc2, (float*)d_out);
}

// Round 5
// 194.592 us; speedup vs baseline: 1.3500x; 1.3500x over previous
//
#include <hip/hip_runtime.h>
#include <hip/hip_bf16.h>

typedef __bf16 bf16;
typedef __bf16 bf16x8 __attribute__((ext_vector_type(8)));
typedef float f32x4 __attribute__((ext_vector_type(4)));

#define C_DIM 128
#define LDA 136   // xn1/O/xn2/sY row stride (bf16 elems)
#define LDQ 40    // q/k row stride
#define LDVT 72   // vT row stride
#define LDP 72    // P row stride
#define LDH 264   // h-half row stride

__device__ __forceinline__ f32x4 mfma16(bf16x8 a, bf16x8 b, f32x4 c) {
  return __builtin_amdgcn_mfma_f32_16x16x32_bf16(a, b, c, 0, 0, 0);
}

// LDS layout (76800 B, 2 blocks/CU at 512 threads = 16 waves/CU):
//   @0     (17408): xn1 -> O -> xn2
//   @17408 (40960): sQ[4][64][40]+sK[4][64][40] -> sP[4][64][72] -> sH[64][264]
//   @58368 (18432): sVT[4][32][72] -> sY[64][136]
// 8 waves: QKV 3 nt/wave; attn 2 waves/head; proj/FC2 1 col-tile/wave; FC1 2 tiles/wave/half.

__global__ __launch_bounds__(512, 4) void swin_fused(
    const float* __restrict__ x,
    const bf16*  __restrict__ Wqkv_t, const float* __restrict__ b_qkv,
    const bf16*  __restrict__ Wout_t, const float* __restrict__ b_out,
    const float* __restrict__ btabx,
    const float* __restrict__ g1, const float* __restrict__ be1,
    const float* __restrict__ g2, const float* __restrict__ be2,
    const bf16*  __restrict__ Wfc1_t, const float* __restrict__ b_fc1,
    const bf16*  __restrict__ Wfc2_t, const float* __restrict__ b_fc2,
    float* __restrict__ out)
{
  __shared__ __attribute__((aligned(16))) char smem[76800];
  bf16 (*sA)[LDA]       = (bf16(*)[LDA])(smem);              // xn1 -> O -> xn2
  bf16 (*sQ)[64][LDQ]   = (bf16(*)[64][LDQ])(smem + 17408);
  bf16 (*sK)[64][LDQ]   = (bf16(*)[64][LDQ])(smem + 37888);
  bf16 (*sP)[64][LDP]   = (bf16(*)[64][LDP])(smem + 17408);  // overlays sQ/sK
  bf16 (*sH)[LDH]       = (bf16(*)[LDH])(smem + 17408);      // overlays sP
  bf16 (*sVT)[32][LDVT] = (bf16(*)[32][LDVT])(smem + 58368);
  bf16 (*sY)[LDA]       = (bf16(*)[LDA])(smem + 58368);      // overlays sVT

  const int tid = threadIdx.x;
  const int w   = tid >> 6;   // wave 0..7
  const int l   = tid & 63;
  const int l15 = l & 15;
  const int lhi = l >> 4;     // 0..3

  const int win = blockIdx.x;
  const int b   = win >> 6;
  const int wy  = (win >> 3) & 7;
  const int wx  = win & 7;
  const int rowbase = b * 4096 + wy * 512 + wx * 8; // t = rowbase + (n>>3)*64 + (n&7)

  // ---------------- Phase 1: LN1 -> sA (xn1) ----------------
  {
    const int tok = tid >> 3, seg = tid & 7;   // 8 lanes per token, 16 f32 each
    const int t = rowbase + (tok >> 3) * 64 + (tok & 7);
    const float* xr = x + (size_t)t * C_DIM + seg * 16;
    float f[16]; float s = 0.f, s2 = 0.f;
    #pragma unroll
    for (int i = 0; i < 4; i++) {
      f32x4 v = *(const f32x4*)(xr + i * 4);
      #pragma unroll
      for (int j = 0; j < 4; j++) { float a = v[j]; f[i*4+j] = a; s += a; s2 += a*a; }
    }
    s  += __shfl_xor(s, 1);  s  += __shfl_xor(s, 2);  s  += __shfl_xor(s, 4);
    s2 += __shfl_xor(s2, 1); s2 += __shfl_xor(s2, 2); s2 += __shfl_xor(s2, 4);
    float mu = s * (1.f/128.f);
    float rs = rsqrtf(s2 * (1.f/128.f) - mu*mu + 1e-5f);
    #pragma unroll
    for (int i = 0; i < 2; i++) {
      f32x4 gv0 = *(const f32x4*)(g1  + seg*16 + i*8);
      f32x4 gv1 = *(const f32x4*)(g1  + seg*16 + i*8 + 4);
      f32x4 bv0 = *(const f32x4*)(be1 + seg*16 + i*8);
      f32x4 bv1 = *(const f32x4*)(be1 + seg*16 + i*8 + 4);
      bf16x8 o;
      #pragma unroll
      for (int j = 0; j < 4; j++) {
        o[j]   = (bf16)((f[i*8+j]   - mu) * rs * gv0[j] + bv0[j]);
        o[j+4] = (bf16)((f[i*8+j+4] - mu) * rs * gv1[j] + bv1[j]);
      }
      *(bf16x8*)&sA[tok][seg*16 + i*8] = o;
    }
  }
  __syncthreads();  // BAR1: xn1 ready

  // ---------------- Phase 2: QKV GEMM (M=64,N=384,K=128), wave w owns nt 3w..3w+2 ----------------
  {
    bf16x8 a[4][4];
    #pragma unroll
    for (int mt = 0; mt < 4; mt++)
      #pragma unroll
      for (int ks = 0; ks < 4; ks++)
        a[mt][ks] = *(const bf16x8*)&sA[mt*16 + l15][ks*32 + lhi*8];
    const float scale = 0.17677669529663687f; // 1/sqrt(32)
    #pragma unroll
    for (int nti = 0; nti < 3; nti++) {
      const int nt = w * 3 + nti;
      const int colg = nt * 16 + l15;           // 0..383
      const bf16* wp = Wqkv_t + (size_t)colg * 128 + lhi * 8;
      bf16x8 bw[4];
      #pragma unroll
      for (int ks = 0; ks < 4; ks++) bw[ks] = *(const bf16x8*)(wp + ks * 32);
      const float bias = b_qkv[colg];
      const int kind = colg >> 7;               // 0=q 1=k 2=v (uniform per nt)
      const int h    = (colg >> 5) & 3;
      const int d    = colg & 31;
      #pragma unroll
      for (int mt = 0; mt < 4; mt++) {
        f32x4 acc = {0.f, 0.f, 0.f, 0.f};
        #pragma unroll
        for (int ks = 0; ks < 4; ks++) acc = mfma16(a[mt][ks], bw[ks], acc);
        #pragma unroll
        for (int r = 0; r < 4; r++) {
          const int token = mt*16 + lhi*4 + r;
          float v = acc[r] + bias;
          if (kind == 0)      sQ[h][token][d] = (bf16)(v * scale);
          else if (kind == 1) sK[h][token][d] = (bf16)v;
          else                sVT[h][d][token] = (bf16)v;
        }
      }
    }
  }
  __syncthreads();  // BAR2: q/k/vT ready

  // ---------------- Phase 3: attention, 2 waves per head; wave owns 2 row-tiles ----------------
  {
    const int h    = w >> 1;
    const int half = w & 1;     // row-tile base = half*2
    bf16x8 aq[2], bk[4];
    #pragma unroll
    for (int mtl = 0; mtl < 2; mtl++)
      aq[mtl] = *(const bf16x8*)&sQ[h][(half*2 + mtl)*16 + l15][lhi*8];
    #pragma unroll
    for (int ct = 0; ct < 4; ct++) bk[ct] = *(const bf16x8*)&sK[h][ct*16 + l15][lhi*8];
    f32x4 sc[2][4];
    #pragma unroll
    for (int mtl = 0; mtl < 2; mtl++)
      #pragma unroll
      for (int ct = 0; ct < 4; ct++) {
        f32x4 z = {0.f, 0.f, 0.f, 0.f};
        sc[mtl][ct] = mfma16(aq[mtl], bk[ct], z);
      }
    __syncthreads();  // BAR3: sQ/sK consumed -> region free for sP
    // bias + softmax rows -> P (bf16, row-major for PV A-operand)
    #pragma unroll
    for (int mtl = 0; mtl < 2; mtl++) {
      #pragma unroll
      for (int r = 0; r < 4; r++) {
        const int n = (half*2 + mtl)*16 + lhi*4 + r;
        f32x4 bv = *(const f32x4*)(btabx + (((h*64 + n)*16 + l15) << 2));
        float rv[4];
        #pragma unroll
        for (int ct = 0; ct < 4; ct++) rv[ct] = sc[mtl][ct][r] + bv[ct];
        float mx = fmaxf(fmaxf(rv[0], rv[1]), fmaxf(rv[2], rv[3]));
        #pragma unroll
        for (int o = 1; o < 16; o <<= 1) mx = fmaxf(mx, __shfl_xor(mx, o));
        float sum = 0.f;
        #pragma unroll
        for (int ct = 0; ct < 4; ct++) { rv[ct] = __expf(rv[ct] - mx); sum += rv[ct]; }
        #pragma unroll
        for (int o = 1; o < 16; o <<= 1) sum += __shfl_xor(sum, o);
        const float inv = 1.f / sum;
        #pragma unroll
        for (int ct = 0; ct < 4; ct++) sP[h][n][ct*16 + l15] = (bf16)(rv[ct] * inv);
      }
    }
    // PV: O rows for this wave's 2 tiles = P(32x64) @ V(64x32)
    f32x4 o_[2][2];
    #pragma unroll
    for (int mtl = 0; mtl < 2; mtl++) { f32x4 z = {0.f,0.f,0.f,0.f}; o_[mtl][0] = z; o_[mtl][1] = z; }
    #pragma unroll
    for (int ks = 0; ks < 2; ks++) {
      bf16x8 ap[2], bvv[2];
      #pragma unroll
      for (int mtl = 0; mtl < 2; mtl++)
        ap[mtl] = *(const bf16x8*)&sP[h][(half*2 + mtl)*16 + l15][ks*32 + lhi*8];
      #pragma unroll
      for (int c2 = 0; c2 < 2; c2++)
        bvv[c2] = *(const bf16x8*)&sVT[h][c2*16 + l15][ks*32 + lhi*8];
      #pragma unroll
      for (int mtl = 0; mtl < 2; mtl++)
        #pragma unroll
        for (int c2 = 0; c2 < 2; c2++) o_[mtl][c2] = mfma16(ap[mtl], bvv[c2], o_[mtl][c2]);
    }
    #pragma unroll
    for (int mtl = 0; mtl < 2; mtl++)
      #pragma unroll
      for (int c2 = 0; c2 < 2; c2++)
        #pragma unroll
        for (int r = 0; r < 4; r++)
          sA[(half*2 + mtl)*16 + lhi*4 + r][h*32 + c2*16 + l15] = (bf16)o_[mtl][c2][r];
  }
  __syncthreads();  // BAR4: O ready (sVT fully consumed)

  // ---------------- Phase 4: out-proj + shortcut -> sY (bf16); wave w owns col-tile w ----------------
  {
    bf16x8 a[4][4];
    #pragma unroll
    for (int mt = 0; mt < 4; mt++)
      #pragma unroll
      for (int ks = 0; ks < 4; ks++)
        a[mt][ks] = *(const bf16x8*)&sA[mt*16 + l15][ks*32 + lhi*8];
    const int col = w * 16 + l15;
    const bf16* wp = Wout_t + (size_t)col * 128 + lhi * 8;
    bf16x8 bw[4];
    #pragma unroll
    for (int ks = 0; ks < 4; ks++) bw[ks] = *(const bf16x8*)(wp + ks * 32);
    const float bo = b_out[col];
    #pragma unroll
    for (int mt = 0; mt < 4; mt++) {
      f32x4 acc = {0.f, 0.f, 0.f, 0.f};
      #pragma unroll
      for (int ks = 0; ks < 4; ks++) acc = mfma16(a[mt][ks], bw[ks], acc);
      #pragma unroll
      for (int r = 0; r < 4; r++) {
        const int token = mt*16 + lhi*4 + r;
        const int t = rowbase + (token >> 3) * 64 + (token & 7);
        float v = acc[r] + bo + x[(size_t)t * C_DIM + col];
        sY[token][col] = (bf16)v;   // sVT dead since BAR4
      }
    }
  }
  __syncthreads();  // BAR5: sY ready; O consumed -> @0 free for xn2

  // ---------------- Phase 5: LN2 (sY -> sA as xn2) ----------------
  {
    const int tok = tid >> 3, seg = tid & 7;
    float f[16]; float s = 0.f, s2 = 0.f;
    #pragma unroll
    for (int i = 0; i < 2; i++) {
      bf16x8 v = *(const bf16x8*)&sY[tok][seg*16 + i*8];
      #pragma unroll
      for (int j = 0; j < 8; j++) { float a = (float)v[j]; f[i*8+j] = a; s += a; s2 += a*a; }
    }
    s  += __shfl_xor(s, 1);  s  += __shfl_xor(s, 2);  s  += __shfl_xor(s, 4);
    s2 += __shfl_xor(s2, 1); s2 += __shfl_xor(s2, 2); s2 += __shfl_xor(s2, 4);
    float mu = s * (1.f/128.f);
    float rs = rsqrtf(s2 * (1.f/128.f) - mu*mu + 1e-5f);
    #pragma unroll
    for (int i = 0; i < 2; i++) {
      f32x4 gv0 = *(const f32x4*)(g2  + seg*16 + i*8);
      f32x4 gv1 = *(const f32x4*)(g2  + seg*16 + i*8 + 4);
      f32x4 bv0 = *(const f32x4*)(be2 + seg*16 + i*8);
      f32x4 bv1 = *(const f32x4*)(be2 + seg*16 + i*8 + 4);
      bf16x8 o;
      #pragma unroll
      for (int j = 0; j < 4; j++) {
        o[j]   = (bf16)((f[i*8+j]   - mu) * rs * gv0[j] + bv0[j]);
        o[j+4] = (bf16)((f[i*8+j+4] - mu) * rs * gv1[j] + bv1[j]);
      }
      *(bf16x8*)&sA[tok][seg*16 + i*8] = o;
    }
  }
  __syncthreads();  // BAR6: xn2 ready

  // ---------------- Phase 6: MLP; wave w owns out col-tile w, 2 FC1 tiles per half ----------------
  {
    bf16x8 a[4][4];
    #pragma unroll
    for (int mt = 0; mt < 4; mt++)
      #pragma unroll
      for (int ks = 0; ks < 4; ks++)
        a[mt][ks] = *(const bf16x8*)&sA[mt*16 + l15][ks*32 + lhi*8];
    f32x4 accF[4];
    #pragma unroll
    for (int mt = 0; mt < 4; mt++) { f32x4 z = {0.f,0.f,0.f,0.f}; accF[mt] = z; }

    #pragma unroll
    for (int hf = 0; hf < 2; hf++) {
      // FC1 half: wave w owns local hidden tiles w*2, w*2+1 of this half
      #pragma unroll
      for (int nti = 0; nti < 2; nti++) {
        const int ntg    = hf*16 + w*2 + nti;          // global hidden tile 0..31
        const int colh   = ntg*16 + l15;               // global hidden col
        const int colloc = (w*2 + nti)*16 + l15;       // col within sH half
        const bf16* wp = Wfc1_t + (size_t)colh * 128 + lhi * 8;
        bf16x8 bw[4];
        #pragma unroll
        for (int ks = 0; ks < 4; ks++) bw[ks] = *(const bf16x8*)(wp + ks * 32);
        const float bb = b_fc1[colh];
        #pragma unroll
        for (int mt = 0; mt < 4; mt++) {
          f32x4 acc = {0.f, 0.f, 0.f, 0.f};
          #pragma unroll
          for (int ks = 0; ks < 4; ks++) acc = mfma16(a[mt][ks], bw[ks], acc);
          #pragma unroll
          for (int r = 0; r < 4; r++) {
            float v = acc[r] + bb;
            // GELU (erf) via tanh form, hardware exp; |err| < ~1e-3 absolute
            float u = v * (0.7978845608028654f + 0.0356774081363001f * v * v);
            float e = __expf(2.f * u);
            float th = 1.f - 2.f / (e + 1.f);
            float g = 0.5f * v * (1.f + th);
            sH[mt*16 + lhi*4 + r][colloc] = (bf16)g;
          }
        }
      }
      __syncthreads();
      // FC2 partial over this half's 256 hidden dims; wave w owns out cols w*16..w*16+15
      #pragma unroll
      for (int ks = 0; ks < 8; ks++) {
        bf16x8 ah[4];
        #pragma unroll
        for (int mt = 0; mt < 4; mt++) ah[mt] = *(const bf16x8*)&sH[mt*16 + l15][ks*32 + lhi*8];
        bf16x8 bw2 = *(const bf16x8*)(Wfc2_t + (size_t)(w*16 + l15) * 512 + hf*256 + ks*32 + lhi*8);
        #pragma unroll
        for (int mt = 0; mt < 4; mt++) accF[mt] = mfma16(ah[mt], bw2, accF[mt]);
      }
      __syncthreads();
    }
    // epilogue: + b_fc2 + y (from sY, bf16) -> out (f32)
    const int col = w*16 + l15;
    const float bb = b_fc2[col];
    #pragma unroll
    for (int mt = 0; mt < 4; mt++)
      #pragma unroll
      for (int r = 0; r < 4; r++) {
        const int token = mt*16 + lhi*4 + r;
        const int t = rowbase + (token >> 3) * 64 + (token & 7);
        out[(size_t)t * C_DIM + col] = accF[mt][r] + bb + (float)sY[token][col];
      }
  }
}

// Transpose f32 weights -> bf16 (W_t[n][k] = W[k][n]) and expand the rel-pos
// bias table to btabx[h][n][l15][ct] = btab[idx(n, ct*16+l15)*4 + h]  (f32)
__global__ void prep_transpose(
    const float* __restrict__ Wqkv, const float* __restrict__ Wout,
    const float* __restrict__ Wfc1, const float* __restrict__ Wfc2,
    const float* __restrict__ btab,
    bf16* __restrict__ Wqkv_t, bf16* __restrict__ Wout_t,
    bf16* __restrict__ Wfc1_t, bf16* __restrict__ Wfc2_t,
    float* __restrict__ btabx)
{
  int i = blockIdx.x * 256 + threadIdx.x;
  if (i < 49152) { int n = i >> 7, k = i & 127; Wqkv_t[i] = (bf16)Wqkv[k*384 + n]; return; }
  i -= 49152;
  if (i < 16384) { int n = i >> 7, k = i & 127; Wout_t[i] = (bf16)Wout[k*128 + n]; return; }
  i -= 16384;
  if (i < 65536) { int n = i >> 7, k = i & 127; Wfc1_t[i] = (bf16)Wfc1[k*512 + n]; return; }
  i -= 65536;
  if (i < 65536) { int n = i >> 9, k = i & 511; Wfc2_t[i] = (bf16)Wfc2[k*128 + n]; return; }
  i -= 65536;
  if (i < 16384) {
    int ct  = i & 3;
    int l15 = (i >> 2) & 15;
    int n   = (i >> 6) & 63;
    int h   = i >> 12;
    int m = ct * 16 + l15;
    int nr = n >> 3, nc = n & 7, mr = m >> 3, mc = m & 7;
    int idx = (nr - mr + 7) * 15 + (nc - mc + 7);
    btabx[i] = btab[idx * 4 + h];
  }
}

extern "C" void kernel_launch(void* const* d_in, const int* in_sizes, int n_in,
                              void* d_out, int out_size, void* d_ws, size_t ws_size,
                              hipStream_t stream)
{
  const float* x    = (const float*)d_in[0];
  const float* Wqkv = (const float*)d_in[1];
  const float* bqkv = (const float*)d_in[2];
  const float* Wout = (const float*)d_in[3];
  const float* bout = (const float*)d_in[4];
  const float* btab = (const float*)d_in[5];
  const float* g1   = (const float*)d_in[6];
  const float* be1  = (const float*)d_in[7];
  const float* g2   = (const float*)d_in[8];
  const float* be2  = (const float*)d_in[9];
  const float* Wfc1 = (const float*)d_in[10];
  const float* bfc1 = (const float*)d_in[11];
  const float* Wfc2 = (const float*)d_in[12];
  const float* bfc2 = (const float*)d_in[13];
  // d_in[14]=H, d_in[15]=W (fixed 64)

  bf16* ws = (bf16*)d_ws;
  bf16* Wqkv_t = ws;            // 384x128
  bf16* Wout_t = ws + 49152;    // 128x128
  bf16* Wfc1_t = ws + 65536;    // 512x128
  bf16* Wfc2_t = ws + 131072;   // 128x512
  float* btabx = (float*)(ws + 196608);  // 4*64*16*4 f32 = 64KB

  prep_transpose<<<832, 256, 0, stream>>>(Wqkv, Wout, Wfc1, Wfc2, btab,
                                          Wqkv_t, Wout_t, Wfc1_t, Wfc2_t, btabx);

  const int B = in_sizes[0] / (4096 * 128);
  swin_fused<<<dim3(B * 64), 512, 0, stream>>>(
      x, Wqkv_t, bqkv, Wout_t, bout, btabx, g1, be1, g2, be2,
      Wfc1_t, bfc1, Wfc2_t, bfc2, (float*)d_out);
}

// Round 6
// 194.444 us; speedup vs baseline: 1.3510x; 1.0008x over previous
//
#include <hip/hip_runtime.h>
#include <hip/hip_bf16.h>

typedef __bf16 bf16;
typedef __bf16 bf16x8 __attribute__((ext_vector_type(8)));
typedef float f32x4 __attribute__((ext_vector_type(4)));

#define C_DIM 128
#define LDA 136   // xn1/O/xn2/sY row stride (bf16 elems)
#define LDQ 40    // q/k row stride
#define LDVT 72   // vT row stride
#define LDP 72    // P row stride
#define LDH 264   // h-half row stride

__device__ __forceinline__ f32x4 mfma16(bf16x8 a, bf16x8 b, f32x4 c) {
  return __builtin_amdgcn_mfma_f32_16x16x32_bf16(a, b, c, 0, 0, 0);
}

// LDS layout (76800 B, 2 blocks/CU at 512 threads = 16 waves/CU):
//   @0     (17408): xn1 -> O -> xn2
//   @17408 (40960): sQ[4][64][40]+sK[4][64][40] -> sP[4][64][72] -> sH[64][264]
//   @58368 (18432): sVT[4][32][72] -> sY[64][136]
// 8 waves: QKV 3 nt/wave; attn 2 waves/head; proj/FC2 1 col-tile/wave; FC1 2 tiles/wave/half.
//
// amdgpu_waves_per_eu(4,4): occupancy is LDS-capped at 2 blocks/CU (= 4 waves/EU),
// so pin the allocator to exactly that -> VGPR budget 128, no heuristic under-allocation.
// (r5: launch_bounds min=4 let hipcc target 8 waves/EU -> 64 VGPR -> ~116 MB spill traffic.)

__global__ __launch_bounds__(512) __attribute__((amdgpu_waves_per_eu(4, 4))) void swin_fused(
    const float* __restrict__ x,
    const bf16*  __restrict__ Wqkv_t, const float* __restrict__ b_qkv,
    const bf16*  __restrict__ Wout_t, const float* __restrict__ b_out,
    const float* __restrict__ btabx,
    const float* __restrict__ g1, const float* __restrict__ be1,
    const float* __restrict__ g2, const float* __restrict__ be2,
    const bf16*  __restrict__ Wfc1_t, const float* __restrict__ b_fc1,
    const bf16*  __restrict__ Wfc2_t, const float* __restrict__ b_fc2,
    float* __restrict__ out)
{
  __shared__ __attribute__((aligned(16))) char smem[76800];
  bf16 (*sA)[LDA]       = (bf16(*)[LDA])(smem);              // xn1 -> O -> xn2
  bf16 (*sQ)[64][LDQ]   = (bf16(*)[64][LDQ])(smem + 17408);
  bf16 (*sK)[64][LDQ]   = (bf16(*)[64][LDQ])(smem + 37888);
  bf16 (*sP)[64][LDP]   = (bf16(*)[64][LDP])(smem + 17408);  // overlays sQ/sK
  bf16 (*sH)[LDH]       = (bf16(*)[LDH])(smem + 17408);      // overlays sP
  bf16 (*sVT)[32][LDVT] = (bf16(*)[32][LDVT])(smem + 58368);
  bf16 (*sY)[LDA]       = (bf16(*)[LDA])(smem + 58368);      // overlays sVT

  const int tid = threadIdx.x;
  const int w   = tid >> 6;   // wave 0..7
  const int l   = tid & 63;
  const int l15 = l & 15;
  const int lhi = l >> 4;     // 0..3

  const int win = blockIdx.x;
  const int b   = win >> 6;
  const int wy  = (win >> 3) & 7;
  const int wx  = win & 7;
  const int rowbase = b * 4096 + wy * 512 + wx * 8; // t = rowbase + (n>>3)*64 + (n&7)

  // ---------------- Phase 1: LN1 -> sA (xn1) ----------------
  {
    const int tok = tid >> 3, seg = tid & 7;   // 8 lanes per token, 16 f32 each
    const int t = rowbase + (tok >> 3) * 64 + (tok & 7);
    const float* xr = x + (size_t)t * C_DIM + seg * 16;
    float f[16]; float s = 0.f, s2 = 0.f;
    #pragma unroll
    for (int i = 0; i < 4; i++) {
      f32x4 v = *(const f32x4*)(xr + i * 4);
      #pragma unroll
      for (int j = 0; j < 4; j++) { float a = v[j]; f[i*4+j] = a; s += a; s2 += a*a; }
    }
    s  += __shfl_xor(s, 1);  s  += __shfl_xor(s, 2);  s  += __shfl_xor(s, 4);
    s2 += __shfl_xor(s2, 1); s2 += __shfl_xor(s2, 2); s2 += __shfl_xor(s2, 4);
    float mu = s * (1.f/128.f);
    float rs = rsqrtf(s2 * (1.f/128.f) - mu*mu + 1e-5f);
    #pragma unroll
    for (int i = 0; i < 2; i++) {
      f32x4 gv0 = *(const f32x4*)(g1  + seg*16 + i*8);
      f32x4 gv1 = *(const f32x4*)(g1  + seg*16 + i*8 + 4);
      f32x4 bv0 = *(const f32x4*)(be1 + seg*16 + i*8);
      f32x4 bv1 = *(const f32x4*)(be1 + seg*16 + i*8 + 4);
      bf16x8 o;
      #pragma unroll
      for (int j = 0; j < 4; j++) {
        o[j]   = (bf16)((f[i*8+j]   - mu) * rs * gv0[j] + bv0[j]);
        o[j+4] = (bf16)((f[i*8+j+4] - mu) * rs * gv1[j] + bv1[j]);
      }
      *(bf16x8*)&sA[tok][seg*16 + i*8] = o;
    }
  }
  __syncthreads();  // BAR1: xn1 ready

  // ---------------- Phase 2: QKV GEMM (M=64,N=384,K=128), wave w owns nt 3w..3w+2 ----------------
  {
    bf16x8 a[4][4];
    #pragma unroll
    for (int mt = 0; mt < 4; mt++)
      #pragma unroll
      for (int ks = 0; ks < 4; ks++)
        a[mt][ks] = *(const bf16x8*)&sA[mt*16 + l15][ks*32 + lhi*8];
    const float scale = 0.17677669529663687f; // 1/sqrt(32)
    #pragma unroll
    for (int nti = 0; nti < 3; nti++) {
      const int nt = w * 3 + nti;
      const int colg = nt * 16 + l15;           // 0..383
      const bf16* wp = Wqkv_t + (size_t)colg * 128 + lhi * 8;
      bf16x8 bw[4];
      #pragma unroll
      for (int ks = 0; ks < 4; ks++) bw[ks] = *(const bf16x8*)(wp + ks * 32);
      const float bias = b_qkv[colg];
      const int kind = colg >> 7;               // 0=q 1=k 2=v (uniform per nt)
      const int h    = (colg >> 5) & 3;
      const int d    = colg & 31;
      #pragma unroll
      for (int mt = 0; mt < 4; mt++) {
        f32x4 acc = {0.f, 0.f, 0.f, 0.f};
        #pragma unroll
        for (int ks = 0; ks < 4; ks++) acc = mfma16(a[mt][ks], bw[ks], acc);
        #pragma unroll
        for (int r = 0; r < 4; r++) {
          const int token = mt*16 + lhi*4 + r;
          float v = acc[r] + bias;
          if (kind == 0)      sQ[h][token][d] = (bf16)(v * scale);
          else if (kind == 1) sK[h][token][d] = (bf16)v;
          else                sVT[h][d][token] = (bf16)v;
        }
      }
    }
  }
  __syncthreads();  // BAR2: q/k/vT ready

  // ---------------- Phase 3: attention, 2 waves per head; wave owns 2 row-tiles ----------------
  {
    const int h    = w >> 1;
    const int half = w & 1;     // row-tile base = half*2
    bf16x8 aq[2], bk[4];
    #pragma unroll
    for (int mtl = 0; mtl < 2; mtl++)
      aq[mtl] = *(const bf16x8*)&sQ[h][(half*2 + mtl)*16 + l15][lhi*8];
    #pragma unroll
    for (int ct = 0; ct < 4; ct++) bk[ct] = *(const bf16x8*)&sK[h][ct*16 + l15][lhi*8];
    f32x4 sc[2][4];
    #pragma unroll
    for (int mtl = 0; mtl < 2; mtl++)
      #pragma unroll
      for (int ct = 0; ct < 4; ct++) {
        f32x4 z = {0.f, 0.f, 0.f, 0.f};
        sc[mtl][ct] = mfma16(aq[mtl], bk[ct], z);
      }
    __syncthreads();  // BAR3: sQ/sK consumed -> region free for sP
    // bias + softmax rows -> P (bf16, row-major for PV A-operand)
    #pragma unroll
    for (int mtl = 0; mtl < 2; mtl++) {
      #pragma unroll
      for (int r = 0; r < 4; r++) {
        const int n = (half*2 + mtl)*16 + lhi*4 + r;
        f32x4 bv = *(const f32x4*)(btabx + (((h*64 + n)*16 + l15) << 2));
        float rv[4];
        #pragma unroll
        for (int ct = 0; ct < 4; ct++) rv[ct] = sc[mtl][ct][r] + bv[ct];
        float mx = fmaxf(fmaxf(rv[0], rv[1]), fmaxf(rv[2], rv[3]));
        #pragma unroll
        for (int o = 1; o < 16; o <<= 1) mx = fmaxf(mx, __shfl_xor(mx, o));
        float sum = 0.f;
        #pragma unroll
        for (int ct = 0; ct < 4; ct++) { rv[ct] = __expf(rv[ct] - mx); sum += rv[ct]; }
        #pragma unroll
        for (int o = 1; o < 16; o <<= 1) sum += __shfl_xor(sum, o);
        const float inv = 1.f / sum;
        #pragma unroll
        for (int ct = 0; ct < 4; ct++) sP[h][n][ct*16 + l15] = (bf16)(rv[ct] * inv);
      }
    }
    // PV: O rows for this wave's 2 tiles = P(32x64) @ V(64x32)
    f32x4 o_[2][2];
    #pragma unroll
    for (int mtl = 0; mtl < 2; mtl++) { f32x4 z = {0.f,0.f,0.f,0.f}; o_[mtl][0] = z; o_[mtl][1] = z; }
    #pragma unroll
    for (int ks = 0; ks < 2; ks++) {
      bf16x8 ap[2], bvv[2];
      #pragma unroll
      for (int mtl = 0; mtl < 2; mtl++)
        ap[mtl] = *(const bf16x8*)&sP[h][(half*2 + mtl)*16 + l15][ks*32 + lhi*8];
      #pragma unroll
      for (int c2 = 0; c2 < 2; c2++)
        bvv[c2] = *(const bf16x8*)&sVT[h][c2*16 + l15][ks*32 + lhi*8];
      #pragma unroll
      for (int mtl = 0; mtl < 2; mtl++)
        #pragma unroll
        for (int c2 = 0; c2 < 2; c2++) o_[mtl][c2] = mfma16(ap[mtl], bvv[c2], o_[mtl][c2]);
    }
    #pragma unroll
    for (int mtl = 0; mtl < 2; mtl++)
      #pragma unroll
      for (int c2 = 0; c2 < 2; c2++)
        #pragma unroll
        for (int r = 0; r < 4; r++)
          sA[(half*2 + mtl)*16 + lhi*4 + r][h*32 + c2*16 + l15] = (bf16)o_[mtl][c2][r];
  }
  __syncthreads();  // BAR4: O ready (sVT fully consumed)

  // ---------------- Phase 4: out-proj + shortcut -> sY (bf16); wave w owns col-tile w ----------------
  {
    bf16x8 a[4][4];
    #pragma unroll
    for (int mt = 0; mt < 4; mt++)
      #pragma unroll
      for (int ks = 0; ks < 4; ks++)
        a[mt][ks] = *(const bf16x8*)&sA[mt*16 + l15][ks*32 + lhi*8];
    const int col = w * 16 + l15;
    const bf16* wp = Wout_t + (size_t)col * 128 + lhi * 8;
    bf16x8 bw[4];
    #pragma unroll
    for (int ks = 0; ks < 4; ks++) bw[ks] = *(const bf16x8*)(wp + ks * 32);
    const float bo = b_out[col];
    #pragma unroll
    for (int mt = 0; mt < 4; mt++) {
      f32x4 acc = {0.f, 0.f, 0.f, 0.f};
      #pragma unroll
      for (int ks = 0; ks < 4; ks++) acc = mfma16(a[mt][ks], bw[ks], acc);
      #pragma unroll
      for (int r = 0; r < 4; r++) {
        const int token = mt*16 + lhi*4 + r;
        const int t = rowbase + (token >> 3) * 64 + (token & 7);
        float v = acc[r] + bo + x[(size_t)t * C_DIM + col];
        sY[token][col] = (bf16)v;   // sVT dead since BAR4
      }
    }
  }
  __syncthreads();  // BAR5: sY ready; O consumed -> @0 free for xn2

  // ---------------- Phase 5: LN2 (sY -> sA as xn2) ----------------
  {
    const int tok = tid >> 3, seg = tid & 7;
    float f[16]; float s = 0.f, s2 = 0.f;
    #pragma unroll
    for (int i = 0; i < 2; i++) {
      bf16x8 v = *(const bf16x8*)&sY[tok][seg*16 + i*8];
      #pragma unroll
      for (int j = 0; j < 8; j++) { float a = (float)v[j]; f[i*8+j] = a; s += a; s2 += a*a; }
    }
    s  += __shfl_xor(s, 1);  s  += __shfl_xor(s, 2);  s  += __shfl_xor(s, 4);
    s2 += __shfl_xor(s2, 1); s2 += __shfl_xor(s2, 2); s2 += __shfl_xor(s2, 4);
    float mu = s * (1.f/128.f);
    float rs = rsqrtf(s2 * (1.f/128.f) - mu*mu + 1e-5f);
    #pragma unroll
    for (int i = 0; i < 2; i++) {
      f32x4 gv0 = *(const f32x4*)(g2  + seg*16 + i*8);
      f32x4 gv1 = *(const f32x4*)(g2  + seg*16 + i*8 + 4);
      f32x4 bv0 = *(const f32x4*)(be2 + seg*16 + i*8);
      f32x4 bv1 = *(const f32x4*)(be2 + seg*16 + i*8 + 4);
      bf16x8 o;
      #pragma unroll
      for (int j = 0; j < 4; j++) {
        o[j]   = (bf16)((f[i*8+j]   - mu) * rs * gv0[j] + bv0[j]);
        o[j+4] = (bf16)((f[i*8+j+4] - mu) * rs * gv1[j] + bv1[j]);
      }
      *(bf16x8*)&sA[tok][seg*16 + i*8] = o;
    }
  }
  __syncthreads();  // BAR6: xn2 ready

  // ---------------- Phase 6: MLP; wave w owns out col-tile w, 2 FC1 tiles per half ----------------
  {
    bf16x8 a[4][4];
    #pragma unroll
    for (int mt = 0; mt < 4; mt++)
      #pragma unroll
      for (int ks = 0; ks < 4; ks++)
        a[mt][ks] = *(const bf16x8*)&sA[mt*16 + l15][ks*32 + lhi*8];
    f32x4 accF[4];
    #pragma unroll
    for (int mt = 0; mt < 4; mt++) { f32x4 z = {0.f,0.f,0.f,0.f}; accF[mt] = z; }

    #pragma unroll
    for (int hf = 0; hf < 2; hf++) {
      // FC1 half: wave w owns local hidden tiles w*2, w*2+1 of this half
      #pragma unroll
      for (int nti = 0; nti < 2; nti++) {
        const int ntg    = hf*16 + w*2 + nti;          // global hidden tile 0..31
        const int colh   = ntg*16 + l15;               // global hidden col
        const int colloc = (w*2 + nti)*16 + l15;       // col within sH half
        const bf16* wp = Wfc1_t + (size_t)colh * 128 + lhi * 8;
        bf16x8 bw[4];
        #pragma unroll
        for (int ks = 0; ks < 4; ks++) bw[ks] = *(const bf16x8*)(wp + ks * 32);
        const float bb = b_fc1[colh];
        #pragma unroll
        for (int mt = 0; mt < 4; mt++) {
          f32x4 acc = {0.f, 0.f, 0.f, 0.f};
          #pragma unroll
          for (int ks = 0; ks < 4; ks++) acc = mfma16(a[mt][ks], bw[ks], acc);
          #pragma unroll
          for (int r = 0; r < 4; r++) {
            float v = acc[r] + bb;
            // GELU (erf) via tanh form, hardware exp; |err| < ~1e-3 absolute
            float u = v * (0.7978845608028654f + 0.0356774081363001f * v * v);
            float e = __expf(2.f * u);
            float th = 1.f - 2.f / (e + 1.f);
            float g = 0.5f * v * (1.f + th);
            sH[mt*16 + lhi*4 + r][colloc] = (bf16)g;
          }
        }
      }
      __syncthreads();
      // FC2 partial over this half's 256 hidden dims; wave w owns out cols w*16..w*16+15
      #pragma unroll
      for (int ks = 0; ks < 8; ks++) {
        bf16x8 ah[4];
        #pragma unroll
        for (int mt = 0; mt < 4; mt++) ah[mt] = *(const bf16x8*)&sH[mt*16 + l15][ks*32 + lhi*8];
        bf16x8 bw2 = *(const bf16x8*)(Wfc2_t + (size_t)(w*16 + l15) * 512 + hf*256 + ks*32 + lhi*8);
        #pragma unroll
        for (int mt = 0; mt < 4; mt++) accF[mt] = mfma16(ah[mt], bw2, accF[mt]);
      }
      __syncthreads();
    }
    // epilogue: + b_fc2 + y (from sY, bf16) -> out (f32)
    const int col = w*16 + l15;
    const float bb = b_fc2[col];
    #pragma unroll
    for (int mt = 0; mt < 4; mt++)
      #pragma unroll
      for (int r = 0; r < 4; r++) {
        const int token = mt*16 + lhi*4 + r;
        const int t = rowbase + (token >> 3) * 64 + (token & 7);
        out[(size_t)t * C_DIM + col] = accF[mt][r] + bb + (float)sY[token][col];
      }
  }
}

// Transpose f32 weights -> bf16 (W_t[n][k] = W[k][n]) and expand the rel-pos
// bias table to btabx[h][n][l15][ct] = btab[idx(n, ct*16+l15)*4 + h]  (f32)
__global__ void prep_transpose(
    const float* __restrict__ Wqkv, const float* __restrict__ Wout,
    const float* __restrict__ Wfc1, const float* __restrict__ Wfc2,
    const float* __restrict__ btab,
    bf16* __restrict__ Wqkv_t, bf16* __restrict__ Wout_t,
    bf16* __restrict__ Wfc1_t, bf16* __restrict__ Wfc2_t,
    float* __restrict__ btabx)
{
  int i = blockIdx.x * 256 + threadIdx.x;
  if (i < 49152) { int n = i >> 7, k = i & 127; Wqkv_t[i] = (bf16)Wqkv[k*384 + n]; return; }
  i -= 49152;
  if (i < 16384) { int n = i >> 7, k = i & 127; Wout_t[i] = (bf16)Wout[k*128 + n]; return; }
  i -= 16384;
  if (i < 65536) { int n = i >> 7, k = i & 127; Wfc1_t[i] = (bf16)Wfc1[k*512 + n]; return; }
  i -= 65536;
  if (i < 65536) { int n = i >> 9, k = i & 511; Wfc2_t[i] = (bf16)Wfc2[k*128 + n]; return; }
  i -= 65536;
  if (i < 16384) {
    int ct  = i & 3;
    int l15 = (i >> 2) & 15;
    int n   = (i >> 6) & 63;
    int h   = i >> 12;
    int m = ct * 16 + l15;
    int nr = n >> 3, nc = n & 7, mr = m >> 3, mc = m & 7;
    int idx = (nr - mr + 7) * 15 + (nc - mc + 7);
    btabx[i] = btab[idx * 4 + h];
  }
}

extern "C" void kernel_launch(void* const* d_in, const int* in_sizes, int n_in,
                              void* d_out, int out_size, void* d_ws, size_t ws_size,
                              hipStream_t stream)
{
  const float* x    = (const float*)d_in[0];
  const float* Wqkv = (const float*)d_in[1];
  const float* bqkv = (const float*)d_in[2];
  const float* Wout = (const float*)d_in[3];
  const float* bout = (const float*)d_in[4];
  const float* btab = (const float*)d_in[5];
  const float* g1   = (const float*)d_in[6];
  const float* be1  = (const float*)d_in[7];
  const float* g2   = (const float*)d_in[8];
  const float* be2  = (const float*)d_in[9];
  const float* Wfc1 = (const float*)d_in[10];
  const float* bfc1 = (const float*)d_in[11];
  const float* Wfc2 = (const float*)d_in[12];
  const float* bfc2 = (const float*)d_in[13];
  // d_in[14]=H, d_in[15]=W (fixed 64)

  bf16* ws = (bf16*)d_ws;
  bf16* Wqkv_t = ws;            // 384x128
  bf16* Wout_t = ws + 49152;    // 128x128
  bf16* Wfc1_t = ws + 65536;    // 512x128
  bf16* Wfc2_t = ws + 131072;   // 128x512
  float* btabx = (float*)(ws + 196608);  // 4*64*16*4 f32 = 64KB

  prep_transpose<<<832, 256, 0, stream>>>(Wqkv, Wout, Wfc1, Wfc2, btab,
                                          Wqkv_t, Wout_t, Wfc1_t, Wfc2_t, btabx);

  const int B = in_sizes[0] / (4096 * 128);
  swin_fused<<<dim3(B * 64), 512, 0, stream>>>(
      x, Wqkv_t, bqkv, Wout_t, bout, btabx, g1, be1, g2, be2,
      Wfc1_t, bfc1, Wfc2_t, bfc2, (float*)d_out);
}